// Round 6
// baseline (40296.179 us; speedup 1.0000x reference)
//
#include <hip/hip_runtime.h>
#include <stdint.h>

#define B_ 16
#define S_ 2048
#define F_ 129
#define H_ 128
#define G_ 512   // 4*H

typedef float f32x4 __attribute__((ext_vector_type(4)));
typedef float f32x4a4 __attribute__((ext_vector_type(4), aligned(4)));
typedef short s16x8 __attribute__((ext_vector_type(8)));
typedef _Float16 f16x8 __attribute__((ext_vector_type(8)));
typedef _Float16 f16x4 __attribute__((ext_vector_type(4)));

// LDS-only barrier: waits ds ops, does NOT drain vmcnt.
#define BAR_LDS() __asm__ volatile("s_waitcnt lgkmcnt(0)\n\ts_barrier" ::: "memory")

#define L2E 1.44269504088896f

__device__ inline unsigned short h2bits(_Float16 h) {
  union { _Float16 h; unsigned short u; } v; v.h = h; return v.u;
}
__device__ inline unsigned short f2h(float f) { return h2bits((_Float16)f); }
__device__ inline float rcp_(float x) { return __builtin_amdgcn_rcpf(x); }
__device__ inline float exp2_(float x) {
  float r; __asm__("v_exp_f32 %0, %1" : "=v"(r) : "v"(x)); return r;
}

// tid0 spins on a device-scope flag (bounded by a block-global deadline so a
// broken protocol produces a WRONG ANSWER, never a hang), then block barrier.
__device__ inline void wait_flag(int* f, int tgt, int tid, long deadline) {
  if (tid == 0) {
    while (__hip_atomic_load(f, __ATOMIC_ACQUIRE, __HIP_MEMORY_SCOPE_AGENT) < tgt) {
      __builtin_amdgcn_s_sleep(8);
      if ((long)__builtin_amdgcn_s_memrealtime() > deadline) break;
    }
  }
  __syncthreads();
}

// ---------------------------------------------------------------------------
// mega_kernel round 19: R18 minus the untested moving parts, plus hang-proof
// spins. blockIdx roles (R3-proven in-order dispatch), STATIC xg assignment
// (worker W owns tiles 2W,2W+1 chunk-major; no ticket queue), every spin
// bounded by a ~40-160ms deadline (legit max wait ~1ms).
//  blocks 0-3   : lstm scan (4 batches each); waits xgprog[c]; publishes
//                 qprog[c] per 64-step chunk (drained barrier + threadfence
//                 + release-add -- the R3-validated protocol, reversed).
//  blocks 4-259 : workers. W=blk-4; qc=W>>3, bp=W&7. Two 4-wave groups, one
//                 per batch (2bp+g). Phases: X static xg -> R rbf ->
//                 A streaming attn (KV chunks rotated qc,qc+1,...; online
//                 softmax is order-invariant) -> M mlp+logit in LDS.
// LDS 110592B -> 1 block/CU; blocks 256-259 (qc=31) run post-lstm (tail).
// ---------------------------------------------------------------------------
__global__ __launch_bounds__(512, 2) void mega_kernel(
    const float* __restrict__ x, const float* __restrict__ prot,
    const float* __restrict__ W_ih, const float* __restrict__ W_hh,
    const float* __restrict__ b_ih, const float* __restrict__ b_hh,
    const float* __restrict__ Wc, const float* __restrict__ bc,
    const float* __restrict__ Wh, const float* __restrict__ bh,
    float* __restrict__ out,
    _Float16* __restrict__ xg, unsigned short* __restrict__ qbf,
    float* __restrict__ kf, int* __restrict__ xgprog,
    int* __restrict__ qprog) {
  __shared__ __align__(16) char smem[110592];
  int tid = threadIdx.x;
  int blk = blockIdx.x;
  long deadline = (long)__builtin_amdgcn_s_memrealtime() + 4000000L;

  if (blk < 4) {
    // ------------------------- LSTM scan -------------------------
    _Float16 (*hbuf)[4 * 144] = (_Float16 (*)[4 * 144])smem;
    int w = tid >> 6, lane = tid & 63;
    int n16 = lane & 15;
    int q8 = lane >> 4;
    int ab = n16 >> 2;
    int u = (w << 4) | n16;
    int bb = blk * 4;
    f16x8 Wf[4][4];
    #pragma unroll
    for (int ty = 0; ty < 4; ++ty) {
      float gs = (ty == 2) ? (2.f * L2E) : (-L2E);
      #pragma unroll
      for (int kb = 0; kb < 4; ++kb) {
        const float* src = &W_hh[(ty * 128 + u) * H_ + kb * 32 + q8 * 8];
        f16x8 v;
        #pragma unroll
        for (int j = 0; j < 8; ++j) v[j] = (_Float16)(src[j] * gs);
        Wf[ty][kb] = v;
      }
    }
    for (int i = tid; i < 2 * 4 * 144; i += 512)
      ((_Float16*)hbuf)[i] = (_Float16)0.f;
    float c = 0.f;
    int hoff = ab * 144 + q8 * 8;
    const _Float16* h0 = &hbuf[0][hoff];
    const _Float16* h1 = &hbuf[1][hoff];
    _Float16* hw = &hbuf[0][q8 * 144 + u];
    const int hstride = 4 * 144;
    const _Float16* xb = xg + (long)(bb + q8) * S_ * G_ + u * 4;
    unsigned short* qp = qbf + (long)(bb + q8) * S_ * H_ + u - H_;
    const _Float16* xpf = xb + 4 * G_;
    wait_flag(&xgprog[0], 16, tid, deadline);
    wait_flag(&xgprog[1], 16, tid, deadline);
    f16x4 cur[4];
    #pragma unroll
    for (int p = 0; p < 4; ++p) cur[p] = *(const f16x4*)(xb + (long)p * G_);
    unsigned short hvp = 0;
    __syncthreads();
    for (int t = 0; t < S_; t += 4) {
      if ((t & 63) == 8 && t > 8) {
        // publish qbf chunk (t>>6)-1: rows <= t-2 written & drained here
        __syncthreads();             // drains all waves' vmcnt (compiler semantics)
        if (tid == 0) {
          __threadfence();
          __hip_atomic_fetch_add(&qprog[(t >> 6) - 1], 1, __ATOMIC_RELEASE,
                                 __HIP_MEMORY_SCOPE_AGENT);
        }
      }
      if ((t & 63) == 0 && t != 0 && t < 1984)
        wait_flag(&xgprog[(t >> 6) + 1], 16, tid, deadline);
      #pragma unroll
      for (int p = 0; p < 4; ++p) {
        BAR_LDS();
        const _Float16* hsrc = (p & 1) ? h0 : h1;
        f16x8 A[4];
        #pragma unroll
        for (int kb = 0; kb < 4; ++kb)
          A[kb] = *(const f16x8*)(hsrc + kb * 32);
        if (t + p > 0)
          *qp = hvp;
        qp += H_;
        f16x4 xcur = cur[p];
        cur[p] = *(const f16x4*)xpf;
        xpf += G_;
        f32x4 r0a[4], r1a[4];
        #pragma unroll
        for (int ty = 0; ty < 4; ++ty) {
          f32x4 a0, a1;
          a0[0] = (float)xcur[ty]; a0[1] = 0.f; a0[2] = 0.f; a0[3] = 0.f;
          a1[0] = 0.f; a1[1] = 0.f; a1[2] = 0.f; a1[3] = 0.f;
          a0 = __builtin_amdgcn_mfma_f32_16x16x32_f16(A[0], Wf[ty][0], a0, 0, 0, 0);
          a1 = __builtin_amdgcn_mfma_f32_16x16x32_f16(A[2], Wf[ty][2], a1, 0, 0, 0);
          a0 = __builtin_amdgcn_mfma_f32_16x16x32_f16(A[1], Wf[ty][1], a0, 0, 0, 0);
          a1 = __builtin_amdgcn_mfma_f32_16x16x32_f16(A[3], Wf[ty][3], a1, 0, 0, 0);
          r0a[ty] = a0; r1a[ty] = a1;
        }
        float g0 = r0a[0][0] + r1a[0][0];
        float g1 = r0a[1][0] + r1a[1][0];
        float g2 = r0a[2][0] + r1a[2][0];
        float g3 = r0a[3][0] + r1a[3][0];
        float ai = rcp_(1.f + exp2_(g0));
        float af = rcp_(1.f + exp2_(g1));
        float ag = 1.f - 2.f * rcp_(1.f + exp2_(g2));
        float ao = rcp_(1.f + exp2_(g3));
        c = af * c + ai * ag;
        float th = 1.f - 2.f * rcp_(1.f + exp2_(c * (2.f * L2E)));
        float hv = ao * th;
        _Float16 hf = (_Float16)hv;
        hw[(p & 1) * hstride] = hf;
        hvp = h2bits(hf);
      }
    }
    *qp = hvp;
    __syncthreads();
    if (tid == 0) {
      __threadfence();
      __hip_atomic_fetch_add(&qprog[31], 1, __ATOMIC_RELEASE, __HIP_MEMORY_SCOPE_AGENT);
    }
    return;
  }

  // =========================== WORKER ===========================
  int W = blk - 4;
  int qc = W >> 3, bp = W & 7;

  // ------------------ phase X: 2 static xg tiles (chunk-major) ------------------
  {
    _Float16 (*xs)[136] = (_Float16 (*)[136])smem;              // 17408
    _Float16 (*ws)[136] = (_Float16 (*)[136])(smem + 17408);    // 34816
    float* bsum = (float*)(smem + 52224);                        // 2048
    int lane = tid & 63, w = tid >> 6;
    int tw = w & 3, hi = w >> 2;
    int l15 = lane & 15, q = lane >> 4;
    bsum[tid] = b_ih[tid] + b_hh[tid];
    __syncthreads();
    #pragma unroll 1
    for (int half = 0; half < 2; ++half) {
      int T = W * 2 + half;
      int batch = T & 15, chunk = T >> 4;                       // chunk-major
      long R0 = (long)batch * S_ + chunk * 64;
      for (int it = 0; it < 4; ++it) {
        int i = tid + it * 512;
        int r = i >> 5, cx = (i & 31) * 4;
        f32x4a4 v = *(const f32x4a4*)&x[(R0 + r) * 129 + cx];
        f16x4 hq;
        #pragma unroll
        for (int j = 0; j < 4; ++j) hq[j] = (_Float16)v[j];
        *(f16x4*)&xs[r][cx] = hq;
      }
      if (tid < 64) xs[tid][128] = (_Float16)x[(R0 + tid) * 129 + 128];
      __syncthreads();
      f16x8 Bf[4];
      #pragma unroll
      for (int kb = 0; kb < 4; ++kb)
        Bf[kb] = *(const f16x8*)&xs[16 * tw + l15][kb * 32 + q * 8];
      float x128 = (float)xs[16 * tw + l15][128];
      f16x4 res[16];
      #pragma unroll
      for (int cg = 0; cg < 4; ++cg) {
        __syncthreads();
        for (int it = 0; it < 8; ++it) {
          int i = tid + it * 512;
          int r = i >> 5, cc = (i & 31) * 4;
          f32x4a4 v = *(const f32x4a4*)&W_ih[(long)(cg * 128 + r) * 129 + cc];
          f16x4 hq;
          #pragma unroll
          for (int j = 0; j < 4; ++j) hq[j] = (_Float16)v[j];
          *(f16x4*)&ws[r][cc] = hq;
        }
        if (tid < 128) ws[tid][128] = (_Float16)W_ih[(long)(cg * 128 + tid) * 129 + 128];
        __syncthreads();
        float gs = (cg == 2) ? (2.f * L2E) : (-L2E);
        #pragma unroll
        for (int t = 0; t < 4; ++t) {
          int tt = hi * 4 + t;
          f32x4 acc;
          acc[0] = 0.f; acc[1] = 0.f; acc[2] = 0.f; acc[3] = 0.f;
          #pragma unroll
          for (int kb = 0; kb < 4; ++kb) {
            f16x8 Af = *(const f16x8*)&ws[tt * 16 + l15][kb * 32 + q * 8];
            acc = __builtin_amdgcn_mfma_f32_16x16x32_f16(Af, Bf[kb], acc, 0, 0, 0);
          }
          #pragma unroll
          for (int r = 0; r < 4; ++r) {
            int unit = tt * 16 + q * 4 + r;
            float vv = (acc[r] + bsum[cg * 128 + unit] + x128 * (float)ws[unit][128]) * gs;
            res[t * 4 + r][cg] = (_Float16)vv;
          }
        }
      }
      long rowbase = (R0 + 16 * tw + l15) * G_;
      #pragma unroll
      for (int t = 0; t < 4; ++t)
        #pragma unroll
        for (int r = 0; r < 4; ++r)
          *(f16x4*)&xg[rowbase + ((hi * 4 + t) * 16 + q * 4 + r) * 4] = res[t * 4 + r];
      __syncthreads();                // drains vmcnt (compiler) before flag
      if (tid == 0) {
        __threadfence();
        __hip_atomic_fetch_add(&xgprog[chunk], 1, __ATOMIC_RELEASE, __HIP_MEMORY_SCOPE_AGENT);
      }
    }
  }

  // ------------------ phase R: rbf for own rows ------------------
  {
    int wv = tid >> 6, lane = tid & 63;
    #pragma unroll
    for (int tb = 0; tb < 2; ++tb) {
      int batch = bp * 2 + tb;
      for (int k8 = 0; k8 < 8; ++k8) {
        long row = (long)batch * S_ + qc * 64 + k8 * 8 + wv;
        const float* xr = x + row * F_;
        const float* pr = prot + row * F_;
        float ss = 0.f;
        for (int k = lane; k < F_; k += 64) { float d = xr[k] - pr[k]; ss += d * d; }
        #pragma unroll
        for (int off = 32; off; off >>= 1) ss += __shfl_xor(ss, off, 64);
        if (lane == 0) kf[row] = __expf(-ss);
      }
    }
  }

  // ------------------ phase A: streaming flash attention ------------------
  int g = tid >> 8;                  // group (0/1) = waves 0-3 / 4-7
  int gtid = tid & 255;
  int lane = tid & 63;
  int w4 = (tid >> 6) & 3;
  int l15 = lane & 15, q = lane >> 4, koff = q * 8;
  int batch = bp * 2 + g;
  const unsigned short* qbg = qbf + (long)batch * S_ * H_;
  char* gb = smem + g * 46080;
  unsigned short* Ks = (unsigned short*)gb;                    // 17408
  unsigned short* VT = (unsigned short*)(gb + 17408);          // 18432
  unsigned short* Ps = (unsigned short*)(gb + 35840);          // 9216
  unsigned short* Pw = Ps + w4 * 16 * 72;

  wait_flag(&qprog[qc], 4, tid, deadline);
  f16x8 qfrag[4];
  #pragma unroll
  for (int kb = 0; kb < 4; ++kb)
    qfrag[kb] = *(const f16x8*)(qbg + (long)(qc * 64 + w4 * 16 + l15) * H_ + kb * 32 + koff);
  f32x4 oacc[8];
  #pragma unroll
  for (int n = 0; n < 8; ++n)
    #pragma unroll
    for (int r = 0; r < 4; ++r) oacc[n][r] = 0.f;
  float mrow[4], lrow[4];
  #pragma unroll
  for (int r = 0; r < 4; ++r) { mrow[r] = -1e30f; lrow[r] = 0.f; }
  const float scale = 0.08804509063256238f;  // 1/sqrt(129)

  for (int i = 0; i < 32; ++i) {
    int c = (qc + i) & 31;           // rotated order: online softmax is order-invariant
    wait_flag(&qprog[c], 4, tid, deadline);
    {
      int rr = gtid >> 4;
      int c0 = (gtid & 15) * 8;
      #pragma unroll
      for (int pch = 0; pch < 4; ++pch) {
        int r = pch * 16 + rr;
        s16x8 v = *(const s16x8*)(qbg + (long)(c * 64 + r) * H_ + c0);
        *(s16x8*)(&Ks[r * 136 + c0]) = v;
        int rbase = r >> 3, rl = r & 7;
        #pragma unroll
        for (int i8 = 0; i8 < 8; ++i8) {
          int d = c0 + i8;
          VT[d * 72 + ((rbase ^ ((d >> 3) & 7)) << 3) + rl] = (unsigned short)v[i8];
        }
      }
    }
    __syncthreads();
    f32x4 sacc[4];
    #pragma unroll
    for (int n = 0; n < 4; ++n) {
      f32x4 acc;
      #pragma unroll
      for (int r = 0; r < 4; ++r) acc[r] = 0.f;
      #pragma unroll
      for (int kb = 0; kb < 4; ++kb) {
        f16x8 bfrag = *(const f16x8*)(&Ks[(n * 16 + l15) * 136 + kb * 32 + koff]);
        acc = __builtin_amdgcn_mfma_f32_16x16x32_f16(qfrag[kb], bfrag, acc, 0, 0, 0);
      }
      sacc[n] = acc;
    }
    #pragma unroll
    for (int r = 0; r < 4; ++r) {
      float mx = fmaxf(fmaxf(sacc[0][r], sacc[1][r]), fmaxf(sacc[2][r], sacc[3][r]));
      #pragma unroll
      for (int m = 1; m < 16; m <<= 1) mx = fmaxf(mx, __shfl_xor(mx, m, 64));
      mx *= scale;
      float mnew = fmaxf(mrow[r], mx);
      float alpha = __expf(mrow[r] - mnew);
      mrow[r] = mnew;
      float psum = 0.f;
      #pragma unroll
      for (int n = 0; n < 4; ++n) {
        float pv = __expf(sacc[n][r] * scale - mnew);
        sacc[n][r] = pv;
        psum += pv;
      }
      #pragma unroll
      for (int m = 1; m < 16; m <<= 1) psum += __shfl_xor(psum, m, 64);
      lrow[r] = lrow[r] * alpha + psum;
      #pragma unroll
      for (int n = 0; n < 8; ++n) oacc[n][r] *= alpha;
    }
    #pragma unroll
    for (int n = 0; n < 4; ++n)
      #pragma unroll
      for (int r = 0; r < 4; ++r)
        Pw[(q * 4 + r) * 72 + n * 16 + l15] = f2h(sacc[n][r]);
    __syncthreads();
    #pragma unroll
    for (int kb = 0; kb < 2; ++kb) {
      f16x8 afrag = *(const f16x8*)(&Pw[l15 * 72 + kb * 32 + koff]);
      #pragma unroll
      for (int n = 0; n < 8; ++n) {
        int d = n * 16 + l15;
        int rb = ((kb * 32 + koff) >> 3) ^ ((d >> 3) & 7);
        f16x8 bfrag = *(const f16x8*)(&VT[d * 72 + (rb << 3)]);
        oacc[n] = __builtin_amdgcn_mfma_f32_16x16x32_f16(afrag, bfrag, oacc[n], 0, 0, 0);
      }
    }
    __syncthreads();
  }

  // ------------------ phase M: mlp + logit (in-LDS context) ------------------
  __syncthreads();                   // both groups done attn; repurpose LDS
  _Float16 (*hb)[64][136] = (_Float16 (*)[64][136])(smem + g * 34816);
  {
    float rl4[4];
    #pragma unroll
    for (int r = 0; r < 4; ++r) rl4[r] = rcp_(lrow[r]);
    #pragma unroll
    for (int n = 0; n < 8; ++n)
      #pragma unroll
      for (int r = 0; r < 4; ++r)
        hb[0][w4 * 16 + q * 4 + r][n * 16 + l15] = (_Float16)(oacc[n][r] * rl4[r]);
    if (gtid < 64) hb[0][gtid][128] = (_Float16)kf[(long)batch * S_ + qc * 64 + gtid];
  }
  _Float16 (*wl)[136] = (_Float16 (*)[136])(smem + 69632);     // 39168
  float* bl = (float*)(smem + 108800);                          // 576
  int cur = 0;
  for (int l = 0; l < 4; ++l) {
    __syncthreads();
    for (int it = 0; it < 9; ++it) {
      int i = tid + it * 512;        // 4608 = 144 rows * 32 quads
      int r = i >> 5, cc = (i & 31) * 4;
      int rs = (r < 129) ? r : 128;
      f32x4a4 v = *(const f32x4a4*)&Wc[((long)l * 129 + rs) * 129 + cc];
      f16x4 hq;
      #pragma unroll
      for (int j = 0; j < 4; ++j) hq[j] = (_Float16)v[j];
      *(f16x4*)&wl[r][cc] = hq;
    }
    if (tid < 144) {
      int rs = (tid < 129) ? tid : 128;
      wl[tid][128] = (_Float16)Wc[((long)l * 129 + rs) * 129 + 128];
      bl[tid] = bc[l * 129 + rs];
    }
    __syncthreads();
    f16x8 Bf[4];
    #pragma unroll
    for (int kb = 0; kb < 4; ++kb)
      Bf[kb] = *(const f16x8*)&hb[cur][16 * w4 + l15][kb * 32 + q * 8];
    float h128 = (float)hb[cur][16 * w4 + l15][128];
    int nxt = cur ^ 1;
    #pragma unroll
    for (int t = 0; t < 9; ++t) {
      f32x4 acc;
      acc[0] = 0.f; acc[1] = 0.f; acc[2] = 0.f; acc[3] = 0.f;
      #pragma unroll
      for (int kb = 0; kb < 4; ++kb) {
        f16x8 Af = *(const f16x8*)&wl[t * 16 + l15][kb * 32 + q * 8];
        acc = __builtin_amdgcn_mfma_f32_16x16x32_f16(Af, Bf[kb], acc, 0, 0, 0);
      }
      f16x4 hv;
      #pragma unroll
      for (int r = 0; r < 4; ++r) {
        int u = t * 16 + q * 4 + r;
        float v = acc[r] + bl[u] + h128 * (float)wl[u][128];
        hv[r] = (_Float16)fmaxf(v, 0.f);
      }
      if (t < 8)
        *(f16x4*)&hb[nxt][16 * w4 + l15][t * 16 + q * 4] = hv;
      else if (q == 0)
        hb[nxt][16 * w4 + l15][128] = hv[0];
    }
    cur ^= 1;
  }
  __syncthreads();
  if (gtid < 128) {
    int row = gtid >> 1, j = gtid & 1;
    float z = bh[j];
    const float* whp = Wh + j * 129;
    for (int k = 0; k < 129; ++k) z += (float)hb[cur][row][k] * whp[k];
    float zo = __shfl_xor(z, 1, 64);
    float mx = fmaxf(z, zo);
    float lse = mx + __logf(__expf(z - mx) + __expf(zo - mx));
    out[((long)batch * S_ + qc * 64 + row) * 2 + j] = z - lse;
  }
}

extern "C" void kernel_launch(void* const* d_in, const int* in_sizes, int n_in,
                              void* d_out, int out_size, void* d_ws, size_t ws_size,
                              hipStream_t stream) {
  const float* x    = (const float*)d_in[0];
  const float* prot = (const float*)d_in[1];
  const float* W_ih = (const float*)d_in[2];
  const float* W_hh = (const float*)d_in[3];
  const float* b_ih = (const float*)d_in[4];
  const float* b_hh = (const float*)d_in[5];
  const float* Wc   = (const float*)d_in[6];
  const float* bc   = (const float*)d_in[7];
  const float* Wh   = (const float*)d_in[8];
  const float* bh   = (const float*)d_in[9];
  float* out = (float*)d_out;
  char* ws = (char*)d_ws;
  _Float16* xgh       = (_Float16*)(ws);                      // 33554432 B
  unsigned short* qbf = (unsigned short*)(ws + 33554432);     //  8388608 B (f16 bits)
  float* kf           = (float*)(ws + 41943040);              //   131072 B
  int* xgprog         = (int*)(ws + 42074112);                //      128 B
  int* qprog          = (int*)(ws + 42074240);                //      128 B

  hipMemsetAsync(ws + 42074112, 0, 512, stream);
  hipLaunchKernelGGL(mega_kernel, dim3(260), dim3(512), 0, stream,
                     x, prot, W_ih, W_hh, b_ih, b_hh, Wc, bc, Wh, bh, out,
                     xgh, qbf, kf, xgprog, qprog);
}

// Round 7
// 1751.722 us; speedup vs baseline: 23.0038x; 23.0038x over previous
//
#include <hip/hip_runtime.h>
#include <stdint.h>

#define B_ 16
#define S_ 2048
#define F_ 129
#define H_ 128
#define G_ 512   // 4*H

typedef float f32x4 __attribute__((ext_vector_type(4)));
typedef float f32x4a4 __attribute__((ext_vector_type(4), aligned(4)));
typedef short s16x8 __attribute__((ext_vector_type(8)));
typedef _Float16 f16x8 __attribute__((ext_vector_type(8)));
typedef _Float16 f16x4 __attribute__((ext_vector_type(4)));

// LDS-only barrier: waits ds ops, does NOT drain vmcnt.
#define BAR_LDS() __asm__ volatile("s_waitcnt lgkmcnt(0)\n\ts_barrier" ::: "memory")

#define L2E 1.44269504088896f

__device__ inline unsigned short h2bits(_Float16 h) {
  union { _Float16 h; unsigned short u; } v; v.h = h; return v.u;
}
__device__ inline unsigned short f2h(float f) { return h2bits((_Float16)f); }
__device__ inline float rcp_(float x) { return __builtin_amdgcn_rcpf(x); }
__device__ inline float exp2_(float x) {
  float r; __asm__("v_exp_f32 %0, %1" : "=v"(r) : "v"(x)); return r;
}

// tid0 spins on a device-scope flag (bounded by a block-global deadline so a
// broken protocol produces a wrong answer + finite duration, never a hang).
__device__ inline void wait_flag(int* f, int tgt, int tid, long deadline) {
  if (tid == 0) {
    while (__hip_atomic_load(f, __ATOMIC_ACQUIRE, __HIP_MEMORY_SCOPE_AGENT) < tgt) {
      __builtin_amdgcn_s_sleep(8);
      if ((long)__builtin_amdgcn_s_memrealtime() > deadline) break;
    }
  }
  __syncthreads();
}

// One 64-row KV chunk of flash attention for one 4-wave group.
// kvc = batch qbf base + c*64*H. 3 internal block barriers (block-uniform).
__device__ __forceinline__ void attn_chunk(
    const unsigned short* kvc, unsigned short* Ks, unsigned short* VT,
    unsigned short* Pw, int gtid, int l15, int q, int koff, float scale,
    f16x8 (&qfrag)[4], f32x4 (&oacc)[8], float (&mrow)[4], float (&lrow)[4]) {
  {
    int rr = gtid >> 4;
    int c0 = (gtid & 15) * 8;
    #pragma unroll
    for (int pch = 0; pch < 4; ++pch) {
      int r = pch * 16 + rr;
      s16x8 v = *(const s16x8*)(kvc + (long)r * H_ + c0);
      *(s16x8*)(&Ks[r * 136 + c0]) = v;
      int rbase = r >> 3, rl = r & 7;
      #pragma unroll
      for (int i8 = 0; i8 < 8; ++i8) {
        int d = c0 + i8;
        VT[d * 72 + ((rbase ^ ((d >> 3) & 7)) << 3) + rl] = (unsigned short)v[i8];
      }
    }
  }
  __syncthreads();
  f32x4 sacc[4];
  #pragma unroll
  for (int n = 0; n < 4; ++n) {
    f32x4 acc;
    #pragma unroll
    for (int r = 0; r < 4; ++r) acc[r] = 0.f;
    #pragma unroll
    for (int kb = 0; kb < 4; ++kb) {
      f16x8 bfrag = *(const f16x8*)(&Ks[(n * 16 + l15) * 136 + kb * 32 + koff]);
      acc = __builtin_amdgcn_mfma_f32_16x16x32_f16(qfrag[kb], bfrag, acc, 0, 0, 0);
    }
    sacc[n] = acc;
  }
  #pragma unroll
  for (int r = 0; r < 4; ++r) {
    float mx = fmaxf(fmaxf(sacc[0][r], sacc[1][r]), fmaxf(sacc[2][r], sacc[3][r]));
    #pragma unroll
    for (int m = 1; m < 16; m <<= 1) mx = fmaxf(mx, __shfl_xor(mx, m, 64));
    mx *= scale;
    float mnew = fmaxf(mrow[r], mx);
    float alpha = __expf(mrow[r] - mnew);
    mrow[r] = mnew;
    float psum = 0.f;
    #pragma unroll
    for (int n = 0; n < 4; ++n) {
      float pv = __expf(sacc[n][r] * scale - mnew);
      sacc[n][r] = pv;
      psum += pv;
    }
    #pragma unroll
    for (int m = 1; m < 16; m <<= 1) psum += __shfl_xor(psum, m, 64);
    lrow[r] = lrow[r] * alpha + psum;
    #pragma unroll
    for (int n = 0; n < 8; ++n) oacc[n][r] *= alpha;
  }
  #pragma unroll
  for (int n = 0; n < 4; ++n)
    #pragma unroll
    for (int r = 0; r < 4; ++r)
      Pw[(q * 4 + r) * 72 + n * 16 + l15] = f2h(sacc[n][r]);
  __syncthreads();
  #pragma unroll
  for (int kb = 0; kb < 2; ++kb) {
    f16x8 afrag = *(const f16x8*)(&Pw[l15 * 72 + kb * 32 + koff]);
    #pragma unroll
    for (int n = 0; n < 8; ++n) {
      int d = n * 16 + l15;
      int rb = ((kb * 32 + koff) >> 3) ^ ((d >> 3) & 7);
      f16x8 bfrag = *(const f16x8*)(&VT[d * 72 + (rb << 3)]);
      oacc[n] = __builtin_amdgcn_mfma_f32_16x16x32_f16(afrag, bfrag, oacc[n], 0, 0, 0);
    }
  }
  __syncthreads();
}

// mlp + logit head for one unit (both groups, each on its own batch).
// R0b = batch*S + qc*64. Starts with a block barrier (protects hb reuse).
__device__ __forceinline__ void mlp_unit(
    char* smem, int tid, int gtid, int g, int w4, int l15, int q,
    const float* Wc, const float* bc, const float* Wh, const float* bh,
    const float* kf, float* out, long R0b,
    f32x4 (&oacc)[8], float (&lrow)[4]) {
  __syncthreads();
  _Float16 (*hb)[64][136] = (_Float16 (*)[64][136])(smem + g * 34816);
  {
    float rl4[4];
    #pragma unroll
    for (int r = 0; r < 4; ++r) rl4[r] = rcp_(lrow[r]);
    #pragma unroll
    for (int n = 0; n < 8; ++n)
      #pragma unroll
      for (int r = 0; r < 4; ++r)
        hb[0][w4 * 16 + q * 4 + r][n * 16 + l15] = (_Float16)(oacc[n][r] * rl4[r]);
    if (gtid < 64) hb[0][gtid][128] = (_Float16)kf[R0b + gtid];
  }
  _Float16 (*wl)[136] = (_Float16 (*)[136])(smem + 69632);     // 39168
  float* bl = (float*)(smem + 108800);                          // 576
  int cur = 0;
  for (int l = 0; l < 4; ++l) {
    __syncthreads();
    for (int it = 0; it < 9; ++it) {
      int i = tid + it * 512;        // 4608 = 144 rows * 32 quads
      int r = i >> 5, cc = (i & 31) * 4;
      int rs = (r < 129) ? r : 128;
      f32x4a4 v = *(const f32x4a4*)&Wc[((long)l * 129 + rs) * 129 + cc];
      f16x4 hq;
      #pragma unroll
      for (int j = 0; j < 4; ++j) hq[j] = (_Float16)v[j];
      *(f16x4*)&wl[r][cc] = hq;
    }
    if (tid < 144) {
      int rs = (tid < 129) ? tid : 128;
      wl[tid][128] = (_Float16)Wc[((long)l * 129 + rs) * 129 + 128];
      bl[tid] = bc[l * 129 + rs];
    }
    __syncthreads();
    f16x8 Bf[4];
    #pragma unroll
    for (int kb = 0; kb < 4; ++kb)
      Bf[kb] = *(const f16x8*)&hb[cur][16 * w4 + l15][kb * 32 + q * 8];
    float h128 = (float)hb[cur][16 * w4 + l15][128];
    int nxt = cur ^ 1;
    #pragma unroll
    for (int t = 0; t < 9; ++t) {
      f32x4 acc;
      acc[0] = 0.f; acc[1] = 0.f; acc[2] = 0.f; acc[3] = 0.f;
      #pragma unroll
      for (int kb = 0; kb < 4; ++kb) {
        f16x8 Af = *(const f16x8*)&wl[t * 16 + l15][kb * 32 + q * 8];
        acc = __builtin_amdgcn_mfma_f32_16x16x32_f16(Af, Bf[kb], acc, 0, 0, 0);
      }
      f16x4 hv;
      #pragma unroll
      for (int r = 0; r < 4; ++r) {
        int u = t * 16 + q * 4 + r;
        float v = acc[r] + bl[u] + h128 * (float)wl[u][128];
        hv[r] = (_Float16)fmaxf(v, 0.f);
      }
      if (t < 8)
        *(f16x4*)&hb[nxt][16 * w4 + l15][t * 16 + q * 4] = hv;
      else if (q == 0)
        hb[nxt][16 * w4 + l15][128] = hv[0];
    }
    cur ^= 1;
  }
  __syncthreads();
  if (gtid < 128) {
    int row = gtid >> 1, j = gtid & 1;
    float z = bh[j];
    const float* whp = Wh + j * 129;
    for (int k = 0; k < 129; ++k) z += (float)hb[cur][row][k] * whp[k];
    float zo = __shfl_xor(z, 1, 64);
    float mx = fmaxf(z, zo);
    float lse = mx + __logf(__expf(z - mx) + __expf(zo - mx));
    out[(R0b + row) * 2 + j] = z - lse;
  }
}

// ---------------------------------------------------------------------------
// mega_kernel round 20: deadlock fixed BY CONSTRUCTION. Grid = 256 = #CUs
// (110KB LDS -> 1 block/CU) so every block is resident from t=0 -- R6's 40ms
// run proved the 260-block layout circular-waited on 4 non-resident workers
// owning half of xg chunk 31. Worker W=blk-4 (0..251) handles attention
// unit A = W+4; workers 0-3 ALSO handle units 0-3 (qc=0 -> their Q exists at
// the first publish, so unit B interleaves inside the chunk loop at ~4us per
// 27us budget). xg tiles: W -> 2W, 2W+1; W<8 -> +504+W (all from resident
// blocks). Rotated KV order per qcA (optimal: Q_qc arrives exactly when
// chunk qc publishes). Deadline spin-guard kept as safety net.
// ---------------------------------------------------------------------------
__global__ __launch_bounds__(512, 2) void mega_kernel(
    const float* __restrict__ x, const float* __restrict__ prot,
    const float* __restrict__ W_ih, const float* __restrict__ W_hh,
    const float* __restrict__ b_ih, const float* __restrict__ b_hh,
    const float* __restrict__ Wc, const float* __restrict__ bc,
    const float* __restrict__ Wh, const float* __restrict__ bh,
    float* __restrict__ out,
    _Float16* __restrict__ xg, unsigned short* __restrict__ qbf,
    float* __restrict__ kf, int* __restrict__ xgprog,
    int* __restrict__ qprog) {
  __shared__ __align__(16) char smem[110592];
  int tid = threadIdx.x;
  int blk = blockIdx.x;
  long deadline = (long)__builtin_amdgcn_s_memrealtime() + 4000000L;

  if (blk < 4) {
    // ------------------------- LSTM scan -------------------------
    _Float16 (*hbuf)[4 * 144] = (_Float16 (*)[4 * 144])smem;
    int w = tid >> 6, lane = tid & 63;
    int n16 = lane & 15;
    int q8 = lane >> 4;
    int ab = n16 >> 2;
    int u = (w << 4) | n16;
    int bb = blk * 4;
    f16x8 Wf[4][4];
    #pragma unroll
    for (int ty = 0; ty < 4; ++ty) {
      float gs = (ty == 2) ? (2.f * L2E) : (-L2E);
      #pragma unroll
      for (int kb = 0; kb < 4; ++kb) {
        const float* src = &W_hh[(ty * 128 + u) * H_ + kb * 32 + q8 * 8];
        f16x8 v;
        #pragma unroll
        for (int j = 0; j < 8; ++j) v[j] = (_Float16)(src[j] * gs);
        Wf[ty][kb] = v;
      }
    }
    for (int i = tid; i < 2 * 4 * 144; i += 512)
      ((_Float16*)hbuf)[i] = (_Float16)0.f;
    float c = 0.f;
    int hoff = ab * 144 + q8 * 8;
    const _Float16* h0 = &hbuf[0][hoff];
    const _Float16* h1 = &hbuf[1][hoff];
    _Float16* hw = &hbuf[0][q8 * 144 + u];
    const int hstride = 4 * 144;
    const _Float16* xb = xg + (long)(bb + q8) * S_ * G_ + u * 4;
    unsigned short* qp = qbf + (long)(bb + q8) * S_ * H_ + u - H_;
    const _Float16* xpf = xb + 4 * G_;
    wait_flag(&xgprog[0], 16, tid, deadline);
    wait_flag(&xgprog[1], 16, tid, deadline);
    f16x4 cur[4];
    #pragma unroll
    for (int p = 0; p < 4; ++p) cur[p] = *(const f16x4*)(xb + (long)p * G_);
    unsigned short hvp = 0;
    __syncthreads();
    for (int t = 0; t < S_; t += 4) {
      if ((t & 63) == 8 && t > 8) {
        // publish qbf chunk (t>>6)-1: rows <= t-2 written & drained here
        __syncthreads();             // drains all waves' vmcnt (compiler semantics)
        if (tid == 0) {
          __threadfence();
          __hip_atomic_fetch_add(&qprog[(t >> 6) - 1], 1, __ATOMIC_RELEASE,
                                 __HIP_MEMORY_SCOPE_AGENT);
        }
      }
      if ((t & 63) == 0 && t != 0 && t < 1984)
        wait_flag(&xgprog[(t >> 6) + 1], 16, tid, deadline);
      #pragma unroll
      for (int p = 0; p < 4; ++p) {
        BAR_LDS();
        const _Float16* hsrc = (p & 1) ? h0 : h1;
        f16x8 A[4];
        #pragma unroll
        for (int kb = 0; kb < 4; ++kb)
          A[kb] = *(const f16x8*)(hsrc + kb * 32);
        if (t + p > 0)
          *qp = hvp;
        qp += H_;
        f16x4 xcur = cur[p];
        cur[p] = *(const f16x4*)xpf;
        xpf += G_;
        f32x4 r0a[4], r1a[4];
        #pragma unroll
        for (int ty = 0; ty < 4; ++ty) {
          f32x4 a0, a1;
          a0[0] = (float)xcur[ty]; a0[1] = 0.f; a0[2] = 0.f; a0[3] = 0.f;
          a1[0] = 0.f; a1[1] = 0.f; a1[2] = 0.f; a1[3] = 0.f;
          a0 = __builtin_amdgcn_mfma_f32_16x16x32_f16(A[0], Wf[ty][0], a0, 0, 0, 0);
          a1 = __builtin_amdgcn_mfma_f32_16x16x32_f16(A[2], Wf[ty][2], a1, 0, 0, 0);
          a0 = __builtin_amdgcn_mfma_f32_16x16x32_f16(A[1], Wf[ty][1], a0, 0, 0, 0);
          a1 = __builtin_amdgcn_mfma_f32_16x16x32_f16(A[3], Wf[ty][3], a1, 0, 0, 0);
          r0a[ty] = a0; r1a[ty] = a1;
        }
        float g0 = r0a[0][0] + r1a[0][0];
        float g1 = r0a[1][0] + r1a[1][0];
        float g2 = r0a[2][0] + r1a[2][0];
        float g3 = r0a[3][0] + r1a[3][0];
        float ai = rcp_(1.f + exp2_(g0));
        float af = rcp_(1.f + exp2_(g1));
        float ag = 1.f - 2.f * rcp_(1.f + exp2_(g2));
        float ao = rcp_(1.f + exp2_(g3));
        c = af * c + ai * ag;
        float th = 1.f - 2.f * rcp_(1.f + exp2_(c * (2.f * L2E)));
        float hv = ao * th;
        _Float16 hf = (_Float16)hv;
        hw[(p & 1) * hstride] = hf;
        hvp = h2bits(hf);
      }
    }
    *qp = hvp;
    __syncthreads();
    if (tid == 0) {
      __threadfence();
      __hip_atomic_fetch_add(&qprog[31], 1, __ATOMIC_RELEASE, __HIP_MEMORY_SCOPE_AGENT);
    }
    return;
  }

  // =========================== WORKER ===========================
  int W = blk - 4;                   // 0..251
  int uA = W + 4;                    // units 4..255
  int qcA = uA >> 3, bpA = uA & 7;
  bool dual = (W < 4);               // also unit B = W (qc=0, bp=W)

  // ------------------ phase X: static xg tiles ------------------
  {
    _Float16 (*xs)[136] = (_Float16 (*)[136])smem;              // 17408
    _Float16 (*ws)[136] = (_Float16 (*)[136])(smem + 17408);    // 34816
    float* bsum = (float*)(smem + 52224);                        // 2048
    int lane = tid & 63, w = tid >> 6;
    int tw = w & 3, hi = w >> 2;
    int l15 = lane & 15, q = lane >> 4;
    bsum[tid] = b_ih[tid] + b_hh[tid];
    __syncthreads();
    int ntile = (W < 8) ? 3 : 2;
    #pragma unroll 1
    for (int half = 0; half < ntile; ++half) {
      int T = (half < 2) ? (2 * W + half) : (504 + W);
      int batch = T & 15, chunk = T >> 4;
      long R0 = (long)batch * S_ + chunk * 64;
      for (int it = 0; it < 4; ++it) {
        int i = tid + it * 512;
        int r = i >> 5, cx = (i & 31) * 4;
        f32x4a4 v = *(const f32x4a4*)&x[(R0 + r) * 129 + cx];
        f16x4 hq;
        #pragma unroll
        for (int j = 0; j < 4; ++j) hq[j] = (_Float16)v[j];
        *(f16x4*)&xs[r][cx] = hq;
      }
      if (tid < 64) xs[tid][128] = (_Float16)x[(R0 + tid) * 129 + 128];
      __syncthreads();
      f16x8 Bf[4];
      #pragma unroll
      for (int kb = 0; kb < 4; ++kb)
        Bf[kb] = *(const f16x8*)&xs[16 * tw + l15][kb * 32 + q * 8];
      float x128 = (float)xs[16 * tw + l15][128];
      f16x4 res[16];
      #pragma unroll
      for (int cg = 0; cg < 4; ++cg) {
        __syncthreads();
        for (int it = 0; it < 8; ++it) {
          int i = tid + it * 512;
          int r = i >> 5, cc = (i & 31) * 4;
          f32x4a4 v = *(const f32x4a4*)&W_ih[(long)(cg * 128 + r) * 129 + cc];
          f16x4 hq;
          #pragma unroll
          for (int j = 0; j < 4; ++j) hq[j] = (_Float16)v[j];
          *(f16x4*)&ws[r][cc] = hq;
        }
        if (tid < 128) ws[tid][128] = (_Float16)W_ih[(long)(cg * 128 + tid) * 129 + 128];
        __syncthreads();
        float gs = (cg == 2) ? (2.f * L2E) : (-L2E);
        #pragma unroll
        for (int t = 0; t < 4; ++t) {
          int tt = hi * 4 + t;
          f32x4 acc;
          acc[0] = 0.f; acc[1] = 0.f; acc[2] = 0.f; acc[3] = 0.f;
          #pragma unroll
          for (int kb = 0; kb < 4; ++kb) {
            f16x8 Af = *(const f16x8*)&ws[tt * 16 + l15][kb * 32 + q * 8];
            acc = __builtin_amdgcn_mfma_f32_16x16x32_f16(Af, Bf[kb], acc, 0, 0, 0);
          }
          #pragma unroll
          for (int r = 0; r < 4; ++r) {
            int unit = tt * 16 + q * 4 + r;
            float vv = (acc[r] + bsum[cg * 128 + unit] + x128 * (float)ws[unit][128]) * gs;
            res[t * 4 + r][cg] = (_Float16)vv;
          }
        }
      }
      long rowbase = (R0 + 16 * tw + l15) * G_;
      #pragma unroll
      for (int t = 0; t < 4; ++t)
        #pragma unroll
        for (int r = 0; r < 4; ++r)
          *(f16x4*)&xg[rowbase + ((hi * 4 + t) * 16 + q * 4 + r) * 4] = res[t * 4 + r];
      __syncthreads();                // drains vmcnt (compiler) before flag
      if (tid == 0) {
        __threadfence();
        __hip_atomic_fetch_add(&xgprog[chunk], 1, __ATOMIC_RELEASE, __HIP_MEMORY_SCOPE_AGENT);
      }
    }
  }

  // ------------------ phase R: rbf for own unit rows ------------------
  {
    int wv = tid >> 6, lane = tid & 63;
    int nrbf = dual ? 4 : 2;
    #pragma unroll 1
    for (int tb = 0; tb < nrbf; ++tb) {
      int batch = (tb < 2) ? (bpA * 2 + tb) : (W * 2 + (tb - 2));
      int rqc = (tb < 2) ? qcA : 0;
      for (int k8 = 0; k8 < 8; ++k8) {
        long row = (long)batch * S_ + rqc * 64 + k8 * 8 + wv;
        const float* xr = x + row * F_;
        const float* pr = prot + row * F_;
        float ss = 0.f;
        for (int k = lane; k < F_; k += 64) { float d = xr[k] - pr[k]; ss += d * d; }
        #pragma unroll
        for (int off = 32; off; off >>= 1) ss += __shfl_xor(ss, off, 64);
        if (lane == 0) kf[row] = __expf(-ss);
      }
    }
  }

  // ------------------ phase A: streaming flash attention ------------------
  int g = tid >> 8;                  // group (0/1) = waves 0-3 / 4-7
  int gtid = tid & 255;
  int lane = tid & 63;
  int w4 = (tid >> 6) & 3;
  int l15 = lane & 15, q = lane >> 4, koff = q * 8;
  int batchA = bpA * 2 + g;
  int batchB = W * 2 + g;            // only used when dual
  const unsigned short* qbA = qbf + (long)batchA * S_ * H_;
  const unsigned short* qbB = qbf + (long)batchB * S_ * H_;
  char* gb = smem + g * 46080;
  unsigned short* Ks = (unsigned short*)gb;                    // 17408
  unsigned short* VT = (unsigned short*)(gb + 17408);          // 18432
  unsigned short* Ps = (unsigned short*)(gb + 35840);          // 9216
  unsigned short* Pw = Ps + w4 * 16 * 72;
  const float scale = 0.08804509063256238f;  // 1/sqrt(129)

  wait_flag(&qprog[qcA], 4, tid, deadline);   // for dual, qcA==0 covers B too
  f16x8 qfA[4], qfB[4];
  #pragma unroll
  for (int kb = 0; kb < 4; ++kb)
    qfA[kb] = *(const f16x8*)(qbA + (long)(qcA * 64 + w4 * 16 + l15) * H_ + kb * 32 + koff);
  if (dual) {
    #pragma unroll
    for (int kb = 0; kb < 4; ++kb)
      qfB[kb] = *(const f16x8*)(qbB + (long)(w4 * 16 + l15) * H_ + kb * 32 + koff);
  }
  f32x4 oaA[8], oaB[8];
  float mA[4], lA[4], mB[4], lB[4];
  #pragma unroll
  for (int n = 0; n < 8; ++n)
    #pragma unroll
    for (int r = 0; r < 4; ++r) { oaA[n][r] = 0.f; oaB[n][r] = 0.f; }
  #pragma unroll
  for (int r = 0; r < 4; ++r) { mA[r] = -1e30f; lA[r] = 0.f; mB[r] = -1e30f; lB[r] = 0.f; }

  for (int i = 0; i < 32; ++i) {
    int c = (qcA + i) & 31;          // rotated: start where Q became available
    wait_flag(&qprog[c], 4, tid, deadline);
    attn_chunk(qbA + (long)c * 64 * H_, Ks, VT, Pw, gtid, l15, q, koff, scale,
               qfA, oaA, mA, lA);
    if (dual)
      attn_chunk(qbB + (long)c * 64 * H_, Ks, VT, Pw, gtid, l15, q, koff, scale,
                 qfB, oaB, mB, lB);
  }

  // ------------------ phase M: mlp + logit per unit ------------------
  mlp_unit(smem, tid, gtid, g, w4, l15, q, Wc, bc, Wh, bh, kf, out,
           (long)batchA * S_ + qcA * 64, oaA, lA);
  if (dual)
    mlp_unit(smem, tid, gtid, g, w4, l15, q, Wc, bc, Wh, bh, kf, out,
             (long)batchB * S_, oaB, lB);
}

extern "C" void kernel_launch(void* const* d_in, const int* in_sizes, int n_in,
                              void* d_out, int out_size, void* d_ws, size_t ws_size,
                              hipStream_t stream) {
  const float* x    = (const float*)d_in[0];
  const float* prot = (const float*)d_in[1];
  const float* W_ih = (const float*)d_in[2];
  const float* W_hh = (const float*)d_in[3];
  const float* b_ih = (const float*)d_in[4];
  const float* b_hh = (const float*)d_in[5];
  const float* Wc   = (const float*)d_in[6];
  const float* bc   = (const float*)d_in[7];
  const float* Wh   = (const float*)d_in[8];
  const float* bh   = (const float*)d_in[9];
  float* out = (float*)d_out;
  char* ws = (char*)d_ws;
  _Float16* xgh       = (_Float16*)(ws);                      // 33554432 B
  unsigned short* qbf = (unsigned short*)(ws + 33554432);     //  8388608 B (f16 bits)
  float* kf           = (float*)(ws + 41943040);              //   131072 B
  int* xgprog         = (int*)(ws + 42074112);                //      128 B
  int* qprog          = (int*)(ws + 42074240);                //      128 B

  hipMemsetAsync(ws + 42074112, 0, 512, stream);
  hipLaunchKernelGGL(mega_kernel, dim3(256), dim3(512), 0, stream,
                     x, prot, W_ih, W_hh, b_ih, b_hh, Wc, bc, Wh, bh, out,
                     xgh, qbf, kf, xgprog, qprog);
}

// Round 8
// 1195.821 us; speedup vs baseline: 33.6975x; 1.4649x over previous
//
#include <hip/hip_runtime.h>
#include <stdint.h>

#define B_ 16
#define S_ 2048
#define F_ 129
#define H_ 128
#define G_ 512   // 4*H

typedef float f32x4 __attribute__((ext_vector_type(4)));
typedef float f32x4a4 __attribute__((ext_vector_type(4), aligned(4)));
typedef short s16x8 __attribute__((ext_vector_type(8)));
typedef _Float16 f16x8 __attribute__((ext_vector_type(8)));
typedef _Float16 f16x4 __attribute__((ext_vector_type(4)));

// LDS-only barrier: waits ds ops, does NOT drain vmcnt.
#define BAR_LDS() __asm__ volatile("s_waitcnt lgkmcnt(0)\n\ts_barrier" ::: "memory")

#define L2E 1.44269504088896f

__device__ inline unsigned short h2bits(_Float16 h) {
  union { _Float16 h; unsigned short u; } v; v.h = h; return v.u;
}
__device__ inline unsigned short f2h(float f) { return h2bits((_Float16)f); }
__device__ inline float rcp_(float x) { return __builtin_amdgcn_rcpf(x); }
__device__ inline float exp2_(float x) {
  float r; __asm__("v_exp_f32 %0, %1" : "=v"(r) : "v"(x)); return r;
}

// tid0 spins with RELAXED agent loads (coherent LLC read, NO L2 invalidate --
// R7's per-poll ACQUIRE was an 8-XCD invalidation storm that stretched the
// lstm window 880->1500+us), then ONE acquire load for the synchronizes-with
// edge (R3-proven visibility: acquire + syncthreads + first-touch reads).
// Deadline-bounded: a broken protocol gives wrong data + finite time, no hang.
__device__ inline void wait_flag(int* f, int tgt, int tid, long deadline) {
  if (tid == 0) {
    if (__hip_atomic_load(f, __ATOMIC_RELAXED, __HIP_MEMORY_SCOPE_AGENT) < tgt) {
      while (__hip_atomic_load(f, __ATOMIC_RELAXED, __HIP_MEMORY_SCOPE_AGENT) < tgt) {
        __builtin_amdgcn_s_sleep(32);
        if ((long)__builtin_amdgcn_s_memrealtime() > deadline) break;
      }
    }
    (void)__hip_atomic_load(f, __ATOMIC_ACQUIRE, __HIP_MEMORY_SCOPE_AGENT);
  }
  __syncthreads();
}

// One 64-row KV chunk of flash attention for one 4-wave group.
// kvc = batch qbf base + c*64*H. 3 internal block barriers (block-uniform).
__device__ __forceinline__ void attn_chunk(
    const unsigned short* kvc, unsigned short* Ks, unsigned short* VT,
    unsigned short* Pw, int gtid, int l15, int q, int koff, float scale,
    f16x8 (&qfrag)[4], f32x4 (&oacc)[8], float (&mrow)[4], float (&lrow)[4]) {
  {
    int rr = gtid >> 4;
    int c0 = (gtid & 15) * 8;
    #pragma unroll
    for (int pch = 0; pch < 4; ++pch) {
      int r = pch * 16 + rr;
      s16x8 v = *(const s16x8*)(kvc + (long)r * H_ + c0);
      *(s16x8*)(&Ks[r * 136 + c0]) = v;
      int rbase = r >> 3, rl = r & 7;
      #pragma unroll
      for (int i8 = 0; i8 < 8; ++i8) {
        int d = c0 + i8;
        VT[d * 72 + ((rbase ^ ((d >> 3) & 7)) << 3) + rl] = (unsigned short)v[i8];
      }
    }
  }
  __syncthreads();
  f32x4 sacc[4];
  #pragma unroll
  for (int n = 0; n < 4; ++n) {
    f32x4 acc;
    #pragma unroll
    for (int r = 0; r < 4; ++r) acc[r] = 0.f;
    #pragma unroll
    for (int kb = 0; kb < 4; ++kb) {
      f16x8 bfrag = *(const f16x8*)(&Ks[(n * 16 + l15) * 136 + kb * 32 + koff]);
      acc = __builtin_amdgcn_mfma_f32_16x16x32_f16(qfrag[kb], bfrag, acc, 0, 0, 0);
    }
    sacc[n] = acc;
  }
  #pragma unroll
  for (int r = 0; r < 4; ++r) {
    float mx = fmaxf(fmaxf(sacc[0][r], sacc[1][r]), fmaxf(sacc[2][r], sacc[3][r]));
    #pragma unroll
    for (int m = 1; m < 16; m <<= 1) mx = fmaxf(mx, __shfl_xor(mx, m, 64));
    mx *= scale;
    float mnew = fmaxf(mrow[r], mx);
    float alpha = __expf(mrow[r] - mnew);
    mrow[r] = mnew;
    float psum = 0.f;
    #pragma unroll
    for (int n = 0; n < 4; ++n) {
      float pv = __expf(sacc[n][r] * scale - mnew);
      sacc[n][r] = pv;
      psum += pv;
    }
    #pragma unroll
    for (int m = 1; m < 16; m <<= 1) psum += __shfl_xor(psum, m, 64);
    lrow[r] = lrow[r] * alpha + psum;
    #pragma unroll
    for (int n = 0; n < 8; ++n) oacc[n][r] *= alpha;
  }
  #pragma unroll
  for (int n = 0; n < 4; ++n)
    #pragma unroll
    for (int r = 0; r < 4; ++r)
      Pw[(q * 4 + r) * 72 + n * 16 + l15] = f2h(sacc[n][r]);
  __syncthreads();
  #pragma unroll
  for (int kb = 0; kb < 2; ++kb) {
    f16x8 afrag = *(const f16x8*)(&Pw[l15 * 72 + kb * 32 + koff]);
    #pragma unroll
    for (int n = 0; n < 8; ++n) {
      int d = n * 16 + l15;
      int rb = ((kb * 32 + koff) >> 3) ^ ((d >> 3) & 7);
      f16x8 bfrag = *(const f16x8*)(&VT[d * 72 + (rb << 3)]);
      oacc[n] = __builtin_amdgcn_mfma_f32_16x16x32_f16(afrag, bfrag, oacc[n], 0, 0, 0);
    }
  }
  __syncthreads();
}

// mlp + logit head for one unit (both groups, each on its own batch).
// R0b = batch*S + qc*64. Starts with a block barrier (protects hb reuse).
__device__ __forceinline__ void mlp_unit(
    char* smem, int tid, int gtid, int g, int w4, int l15, int q,
    const float* Wc, const float* bc, const float* Wh, const float* bh,
    const float* kf, float* out, long R0b,
    f32x4 (&oacc)[8], float (&lrow)[4]) {
  __syncthreads();
  _Float16 (*hb)[64][136] = (_Float16 (*)[64][136])(smem + g * 34816);
  {
    float rl4[4];
    #pragma unroll
    for (int r = 0; r < 4; ++r) rl4[r] = rcp_(lrow[r]);
    #pragma unroll
    for (int n = 0; n < 8; ++n)
      #pragma unroll
      for (int r = 0; r < 4; ++r)
        hb[0][w4 * 16 + q * 4 + r][n * 16 + l15] = (_Float16)(oacc[n][r] * rl4[r]);
    if (gtid < 64) hb[0][gtid][128] = (_Float16)kf[R0b + gtid];
  }
  _Float16 (*wl)[136] = (_Float16 (*)[136])(smem + 69632);     // 39168
  float* bl = (float*)(smem + 108800);                          // 576
  int cur = 0;
  for (int l = 0; l < 4; ++l) {
    __syncthreads();
    for (int it = 0; it < 9; ++it) {
      int i = tid + it * 512;        // 4608 = 144 rows * 32 quads
      int r = i >> 5, cc = (i & 31) * 4;
      int rs = (r < 129) ? r : 128;
      f32x4a4 v = *(const f32x4a4*)&Wc[((long)l * 129 + rs) * 129 + cc];
      f16x4 hq;
      #pragma unroll
      for (int j = 0; j < 4; ++j) hq[j] = (_Float16)v[j];
      *(f16x4*)&wl[r][cc] = hq;
    }
    if (tid < 144) {
      int rs = (tid < 129) ? tid : 128;
      wl[tid][128] = (_Float16)Wc[((long)l * 129 + rs) * 129 + 128];
      bl[tid] = bc[l * 129 + rs];
    }
    __syncthreads();
    f16x8 Bf[4];
    #pragma unroll
    for (int kb = 0; kb < 4; ++kb)
      Bf[kb] = *(const f16x8*)&hb[cur][16 * w4 + l15][kb * 32 + q * 8];
    float h128 = (float)hb[cur][16 * w4 + l15][128];
    int nxt = cur ^ 1;
    #pragma unroll
    for (int t = 0; t < 9; ++t) {
      f32x4 acc;
      acc[0] = 0.f; acc[1] = 0.f; acc[2] = 0.f; acc[3] = 0.f;
      #pragma unroll
      for (int kb = 0; kb < 4; ++kb) {
        f16x8 Af = *(const f16x8*)&wl[t * 16 + l15][kb * 32 + q * 8];
        acc = __builtin_amdgcn_mfma_f32_16x16x32_f16(Af, Bf[kb], acc, 0, 0, 0);
      }
      f16x4 hv;
      #pragma unroll
      for (int r = 0; r < 4; ++r) {
        int u = t * 16 + q * 4 + r;
        float v = acc[r] + bl[u] + h128 * (float)wl[u][128];
        hv[r] = (_Float16)fmaxf(v, 0.f);
      }
      if (t < 8)
        *(f16x4*)&hb[nxt][16 * w4 + l15][t * 16 + q * 4] = hv;
      else if (q == 0)
        hb[nxt][16 * w4 + l15][128] = hv[0];
    }
    cur ^= 1;
  }
  __syncthreads();
  if (gtid < 128) {
    int row = gtid >> 1, j = gtid & 1;
    float z = bh[j];
    const float* whp = Wh + j * 129;
    for (int k = 0; k < 129; ++k) z += (float)hb[cur][row][k] * whp[k];
    float zo = __shfl_xor(z, 1, 64);
    float mx = fmaxf(z, zo);
    float lse = mx + __logf(__expf(z - mx) + __expf(zo - mx));
    out[(R0b + row) * 2 + j] = z - lse;
  }
}

// ---------------------------------------------------------------------------
// mega_kernel round 21 = R20 + two fixes from the 1711us post-mortem:
//  (1) RELAXED spin + single acquire (see wait_flag) -- kills the per-poll
//      L2-invalidation storm (252 blocks x 5 polls/us of agent-ACQUIRE).
//  (2) NATURAL chunk order 0..31 after the Q-wait (qprog[qcA] implies chunks
//      0..qcA all published): backlog consumed at full speed INSIDE the
//      window's idle gaps; every worker's tail = 1 chunk + mlp (~40us).
//      R20's rotation deferred the backlog post-window (qc=31: ~180us tail).
// Grid=256=#CUs (1 block/CU, all resident; R7-proven finite). Deadline
// spin-guard kept as safety net.
// ---------------------------------------------------------------------------
__global__ __launch_bounds__(512, 2) void mega_kernel(
    const float* __restrict__ x, const float* __restrict__ prot,
    const float* __restrict__ W_ih, const float* __restrict__ W_hh,
    const float* __restrict__ b_ih, const float* __restrict__ b_hh,
    const float* __restrict__ Wc, const float* __restrict__ bc,
    const float* __restrict__ Wh, const float* __restrict__ bh,
    float* __restrict__ out,
    _Float16* __restrict__ xg, unsigned short* __restrict__ qbf,
    float* __restrict__ kf, int* __restrict__ xgprog,
    int* __restrict__ qprog) {
  __shared__ __align__(16) char smem[110592];
  int tid = threadIdx.x;
  int blk = blockIdx.x;
  long deadline = (long)__builtin_amdgcn_s_memrealtime() + 4000000L;

  if (blk < 4) {
    // ------------------------- LSTM scan -------------------------
    _Float16 (*hbuf)[4 * 144] = (_Float16 (*)[4 * 144])smem;
    int w = tid >> 6, lane = tid & 63;
    int n16 = lane & 15;
    int q8 = lane >> 4;
    int ab = n16 >> 2;
    int u = (w << 4) | n16;
    int bb = blk * 4;
    f16x8 Wf[4][4];
    #pragma unroll
    for (int ty = 0; ty < 4; ++ty) {
      float gs = (ty == 2) ? (2.f * L2E) : (-L2E);
      #pragma unroll
      for (int kb = 0; kb < 4; ++kb) {
        const float* src = &W_hh[(ty * 128 + u) * H_ + kb * 32 + q8 * 8];
        f16x8 v;
        #pragma unroll
        for (int j = 0; j < 8; ++j) v[j] = (_Float16)(src[j] * gs);
        Wf[ty][kb] = v;
      }
    }
    for (int i = tid; i < 2 * 4 * 144; i += 512)
      ((_Float16*)hbuf)[i] = (_Float16)0.f;
    float c = 0.f;
    int hoff = ab * 144 + q8 * 8;
    const _Float16* h0 = &hbuf[0][hoff];
    const _Float16* h1 = &hbuf[1][hoff];
    _Float16* hw = &hbuf[0][q8 * 144 + u];
    const int hstride = 4 * 144;
    const _Float16* xb = xg + (long)(bb + q8) * S_ * G_ + u * 4;
    unsigned short* qp = qbf + (long)(bb + q8) * S_ * H_ + u - H_;
    const _Float16* xpf = xb + 4 * G_;
    wait_flag(&xgprog[0], 16, tid, deadline);
    wait_flag(&xgprog[1], 16, tid, deadline);
    f16x4 cur[4];
    #pragma unroll
    for (int p = 0; p < 4; ++p) cur[p] = *(const f16x4*)(xb + (long)p * G_);
    unsigned short hvp = 0;
    __syncthreads();
    for (int t = 0; t < S_; t += 4) {
      if ((t & 63) == 8 && t > 8) {
        // publish qbf chunk (t>>6)-1: rows <= t-2 written & drained here
        __syncthreads();             // drains all waves' vmcnt (compiler semantics)
        if (tid == 0) {
          __threadfence();
          __hip_atomic_fetch_add(&qprog[(t >> 6) - 1], 1, __ATOMIC_RELEASE,
                                 __HIP_MEMORY_SCOPE_AGENT);
        }
      }
      if ((t & 63) == 0 && t != 0 && t < 1984)
        wait_flag(&xgprog[(t >> 6) + 1], 16, tid, deadline);
      #pragma unroll
      for (int p = 0; p < 4; ++p) {
        BAR_LDS();
        const _Float16* hsrc = (p & 1) ? h0 : h1;
        f16x8 A[4];
        #pragma unroll
        for (int kb = 0; kb < 4; ++kb)
          A[kb] = *(const f16x8*)(hsrc + kb * 32);
        if (t + p > 0)
          *qp = hvp;
        qp += H_;
        f16x4 xcur = cur[p];
        cur[p] = *(const f16x4*)xpf;
        xpf += G_;
        f32x4 r0a[4], r1a[4];
        #pragma unroll
        for (int ty = 0; ty < 4; ++ty) {
          f32x4 a0, a1;
          a0[0] = (float)xcur[ty]; a0[1] = 0.f; a0[2] = 0.f; a0[3] = 0.f;
          a1[0] = 0.f; a1[1] = 0.f; a1[2] = 0.f; a1[3] = 0.f;
          a0 = __builtin_amdgcn_mfma_f32_16x16x32_f16(A[0], Wf[ty][0], a0, 0, 0, 0);
          a1 = __builtin_amdgcn_mfma_f32_16x16x32_f16(A[2], Wf[ty][2], a1, 0, 0, 0);
          a0 = __builtin_amdgcn_mfma_f32_16x16x32_f16(A[1], Wf[ty][1], a0, 0, 0, 0);
          a1 = __builtin_amdgcn_mfma_f32_16x16x32_f16(A[3], Wf[ty][3], a1, 0, 0, 0);
          r0a[ty] = a0; r1a[ty] = a1;
        }
        float g0 = r0a[0][0] + r1a[0][0];
        float g1 = r0a[1][0] + r1a[1][0];
        float g2 = r0a[2][0] + r1a[2][0];
        float g3 = r0a[3][0] + r1a[3][0];
        float ai = rcp_(1.f + exp2_(g0));
        float af = rcp_(1.f + exp2_(g1));
        float ag = 1.f - 2.f * rcp_(1.f + exp2_(g2));
        float ao = rcp_(1.f + exp2_(g3));
        c = af * c + ai * ag;
        float th = 1.f - 2.f * rcp_(1.f + exp2_(c * (2.f * L2E)));
        float hv = ao * th;
        _Float16 hf = (_Float16)hv;
        hw[(p & 1) * hstride] = hf;
        hvp = h2bits(hf);
      }
    }
    *qp = hvp;
    __syncthreads();
    if (tid == 0) {
      __threadfence();
      __hip_atomic_fetch_add(&qprog[31], 1, __ATOMIC_RELEASE, __HIP_MEMORY_SCOPE_AGENT);
    }
    return;
  }

  // =========================== WORKER ===========================
  int W = blk - 4;                   // 0..251
  int uA = W + 4;                    // units 4..255
  int qcA = uA >> 3, bpA = uA & 7;
  bool dual = (W < 4);               // also unit B = W (qc=0, bp=W)

  // ------------------ phase X: static xg tiles ------------------
  {
    _Float16 (*xs)[136] = (_Float16 (*)[136])smem;              // 17408
    _Float16 (*ws)[136] = (_Float16 (*)[136])(smem + 17408);    // 34816
    float* bsum = (float*)(smem + 52224);                        // 2048
    int lane = tid & 63, w = tid >> 6;
    int tw = w & 3, hi = w >> 2;
    int l15 = lane & 15, q = lane >> 4;
    bsum[tid] = b_ih[tid] + b_hh[tid];
    __syncthreads();
    int ntile = (W < 8) ? 3 : 2;
    #pragma unroll 1
    for (int half = 0; half < ntile; ++half) {
      int T = (half < 2) ? (2 * W + half) : (504 + W);
      int batch = T & 15, chunk = T >> 4;
      long R0 = (long)batch * S_ + chunk * 64;
      for (int it = 0; it < 4; ++it) {
        int i = tid + it * 512;
        int r = i >> 5, cx = (i & 31) * 4;
        f32x4a4 v = *(const f32x4a4*)&x[(R0 + r) * 129 + cx];
        f16x4 hq;
        #pragma unroll
        for (int j = 0; j < 4; ++j) hq[j] = (_Float16)v[j];
        *(f16x4*)&xs[r][cx] = hq;
      }
      if (tid < 64) xs[tid][128] = (_Float16)x[(R0 + tid) * 129 + 128];
      __syncthreads();
      f16x8 Bf[4];
      #pragma unroll
      for (int kb = 0; kb < 4; ++kb)
        Bf[kb] = *(const f16x8*)&xs[16 * tw + l15][kb * 32 + q * 8];
      float x128 = (float)xs[16 * tw + l15][128];
      f16x4 res[16];
      #pragma unroll
      for (int cg = 0; cg < 4; ++cg) {
        __syncthreads();
        for (int it = 0; it < 8; ++it) {
          int i = tid + it * 512;
          int r = i >> 5, cc = (i & 31) * 4;
          f32x4a4 v = *(const f32x4a4*)&W_ih[(long)(cg * 128 + r) * 129 + cc];
          f16x4 hq;
          #pragma unroll
          for (int j = 0; j < 4; ++j) hq[j] = (_Float16)v[j];
          *(f16x4*)&ws[r][cc] = hq;
        }
        if (tid < 128) ws[tid][128] = (_Float16)W_ih[(long)(cg * 128 + tid) * 129 + 128];
        __syncthreads();
        float gs = (cg == 2) ? (2.f * L2E) : (-L2E);
        #pragma unroll
        for (int t = 0; t < 4; ++t) {
          int tt = hi * 4 + t;
          f32x4 acc;
          acc[0] = 0.f; acc[1] = 0.f; acc[2] = 0.f; acc[3] = 0.f;
          #pragma unroll
          for (int kb = 0; kb < 4; ++kb) {
            f16x8 Af = *(const f16x8*)&ws[tt * 16 + l15][kb * 32 + q * 8];
            acc = __builtin_amdgcn_mfma_f32_16x16x32_f16(Af, Bf[kb], acc, 0, 0, 0);
          }
          #pragma unroll
          for (int r = 0; r < 4; ++r) {
            int unit = tt * 16 + q * 4 + r;
            float vv = (acc[r] + bsum[cg * 128 + unit] + x128 * (float)ws[unit][128]) * gs;
            res[t * 4 + r][cg] = (_Float16)vv;
          }
        }
      }
      long rowbase = (R0 + 16 * tw + l15) * G_;
      #pragma unroll
      for (int t = 0; t < 4; ++t)
        #pragma unroll
        for (int r = 0; r < 4; ++r)
          *(f16x4*)&xg[rowbase + ((hi * 4 + t) * 16 + q * 4 + r) * 4] = res[t * 4 + r];
      __syncthreads();                // drains vmcnt (compiler) before flag
      if (tid == 0) {
        __threadfence();
        __hip_atomic_fetch_add(&xgprog[chunk], 1, __ATOMIC_RELEASE, __HIP_MEMORY_SCOPE_AGENT);
      }
    }
  }

  // ------------------ phase R: rbf for own unit rows ------------------
  {
    int wv = tid >> 6, lane = tid & 63;
    int nrbf = dual ? 4 : 2;
    #pragma unroll 1
    for (int tb = 0; tb < nrbf; ++tb) {
      int batch = (tb < 2) ? (bpA * 2 + tb) : (W * 2 + (tb - 2));
      int rqc = (tb < 2) ? qcA : 0;
      for (int k8 = 0; k8 < 8; ++k8) {
        long row = (long)batch * S_ + rqc * 64 + k8 * 8 + wv;
        const float* xr = x + row * F_;
        const float* pr = prot + row * F_;
        float ss = 0.f;
        for (int k = lane; k < F_; k += 64) { float d = xr[k] - pr[k]; ss += d * d; }
        #pragma unroll
        for (int off = 32; off; off >>= 1) ss += __shfl_xor(ss, off, 64);
        if (lane == 0) kf[row] = __expf(-ss);
      }
    }
  }

  // ------------------ phase A: streaming flash attention ------------------
  int g = tid >> 8;                  // group (0/1) = waves 0-3 / 4-7
  int gtid = tid & 255;
  int lane = tid & 63;
  int w4 = (tid >> 6) & 3;
  int l15 = lane & 15, q = lane >> 4, koff = q * 8;
  int batchA = bpA * 2 + g;
  int batchB = W * 2 + g;            // only used when dual
  const unsigned short* qbA = qbf + (long)batchA * S_ * H_;
  const unsigned short* qbB = qbf + (long)batchB * S_ * H_;
  char* gb = smem + g * 46080;
  unsigned short* Ks = (unsigned short*)gb;                    // 17408
  unsigned short* VT = (unsigned short*)(gb + 17408);          // 18432
  unsigned short* Ps = (unsigned short*)(gb + 35840);          // 9216
  unsigned short* Pw = Ps + w4 * 16 * 72;
  const float scale = 0.08804509063256238f;  // 1/sqrt(129)

  wait_flag(&qprog[qcA], 4, tid, deadline);   // Q ready; implies chunks 0..qcA
  f16x8 qfA[4], qfB[4];
  #pragma unroll
  for (int kb = 0; kb < 4; ++kb)
    qfA[kb] = *(const f16x8*)(qbA + (long)(qcA * 64 + w4 * 16 + l15) * H_ + kb * 32 + koff);
  if (dual) {
    #pragma unroll
    for (int kb = 0; kb < 4; ++kb)
      qfB[kb] = *(const f16x8*)(qbB + (long)(w4 * 16 + l15) * H_ + kb * 32 + koff);
  }
  f32x4 oaA[8], oaB[8];
  float mA[4], lA[4], mB[4], lB[4];
  #pragma unroll
  for (int n = 0; n < 8; ++n)
    #pragma unroll
    for (int r = 0; r < 4; ++r) { oaA[n][r] = 0.f; oaB[n][r] = 0.f; }
  #pragma unroll
  for (int r = 0; r < 4; ++r) { mA[r] = -1e30f; lA[r] = 0.f; mB[r] = -1e30f; lB[r] = 0.f; }

  for (int c = 0; c < 32; ++c) {     // natural order: backlog 0..qcA is free,
    wait_flag(&qprog[c], 4, tid, deadline);   // then follow the publish frontier
    attn_chunk(qbA + (long)c * 64 * H_, Ks, VT, Pw, gtid, l15, q, koff, scale,
               qfA, oaA, mA, lA);
    if (dual)
      attn_chunk(qbB + (long)c * 64 * H_, Ks, VT, Pw, gtid, l15, q, koff, scale,
                 qfB, oaB, mB, lB);
  }

  // ------------------ phase M: mlp + logit per unit ------------------
  mlp_unit(smem, tid, gtid, g, w4, l15, q, Wc, bc, Wh, bh, kf, out,
           (long)batchA * S_ + qcA * 64, oaA, lA);
  if (dual)
    mlp_unit(smem, tid, gtid, g, w4, l15, q, Wc, bc, Wh, bh, kf, out,
             (long)batchB * S_, oaB, lB);
}

extern "C" void kernel_launch(void* const* d_in, const int* in_sizes, int n_in,
                              void* d_out, int out_size, void* d_ws, size_t ws_size,
                              hipStream_t stream) {
  const float* x    = (const float*)d_in[0];
  const float* prot = (const float*)d_in[1];
  const float* W_ih = (const float*)d_in[2];
  const float* W_hh = (const float*)d_in[3];
  const float* b_ih = (const float*)d_in[4];
  const float* b_hh = (const float*)d_in[5];
  const float* Wc   = (const float*)d_in[6];
  const float* bc   = (const float*)d_in[7];
  const float* Wh   = (const float*)d_in[8];
  const float* bh   = (const float*)d_in[9];
  float* out = (float*)d_out;
  char* ws = (char*)d_ws;
  _Float16* xgh       = (_Float16*)(ws);                      // 33554432 B
  unsigned short* qbf = (unsigned short*)(ws + 33554432);     //  8388608 B (f16 bits)
  float* kf           = (float*)(ws + 41943040);              //   131072 B
  int* xgprog         = (int*)(ws + 42074112);                //      128 B
  int* qprog          = (int*)(ws + 42074240);                //      128 B

  hipMemsetAsync(ws + 42074112, 0, 512, stream);
  hipLaunchKernelGGL(mega_kernel, dim3(256), dim3(512), 0, stream,
                     x, prot, W_ih, W_hh, b_ih, b_hh, Wc, bc, Wh, bh, out,
                     xgh, qbf, kf, xgprog, qprog);
}